// Round 1
// baseline (158.173 us; speedup 1.0000x reference)
//
#include <hip/hip_runtime.h>

namespace {
constexpr int kB   = 1000;
constexpr int kT   = 20000;
constexpr int kKt  = 181;
constexpr int kInW = kT + kKt - 1;            // 20180
constexpr int BM   = 16;                      // batch rows per block
constexpr int BT   = 512;                     // output cols per block
constexpr int NCHUNK = 7;                     // 7 k-chunks of 32 -> covers k in [0,224) >= 15+181
constexpr int COLS = (BT - 16) + NCHUNK * 32; // 720 staged input cols
constexpr int LDS_STRIDE = COLS + 8;          // 728: stride%32dw==12 -> b128 reads conflict-free

typedef short bf16x8 __attribute__((ext_vector_type(8)));
typedef float f32x4  __attribute__((ext_vector_type(4)));

__device__ __forceinline__ short f32_bf16(float f) {
  union { float f; unsigned u; } x; x.f = f;
  unsigned r = x.u + (0x7fffu + ((x.u >> 16) & 1u));  // RNE
  return (short)(r >> 16);
}
} // namespace

__global__ __launch_bounds__(256, 4)
void biexp_conv_mfma(const float* __restrict__ u, const float* __restrict__ kern,
                     float* __restrict__ out) {
  __shared__ short lds_u[BM * LDS_STRIDE];
  __shared__ float lds_k[kKt];

  const int tid  = threadIdx.x;
  const int lane = tid & 63;
  const int wave = tid >> 6;
  const int quad = lane >> 4;
  const int nn   = lane & 15;
  const int b0 = blockIdx.y * BM;
  const int t0 = blockIdx.x * BT;

  if (tid < kKt) lds_k[tid] = kern[tid];

  // ---- stage u tile (fp32 -> bf16) : rows b0..b0+15 (clamped), cols t0..t0+719 (clamped)
  const int nvec = (COLS / 4) * BM;            // 2880 float4 slots
  for (int f = tid; f < nvec; f += 256) {
    int r  = f / (COLS / 4);
    int c4 = f - r * (COLS / 4);
    int row = b0 + r; row = row < kB ? row : kB - 1;
    int col = t0 + c4 * 4;
    const float* src = u + (size_t)row * kInW;
    float v0, v1, v2, v3;
    if (col + 3 < kInW) {
      float4 v = *(const float4*)(src + col);
      v0 = v.x; v1 = v.y; v2 = v.z; v3 = v.w;
    } else {
      int cm = kInW - 1;
      v0 = src[col     < cm ? col     : cm];
      v1 = src[col + 1 < cm ? col + 1 : cm];
      v2 = src[col + 2 < cm ? col + 2 : cm];
      v3 = src[col + 3 < cm ? col + 3 : cm];
    }
    short4 s;
    s.x = f32_bf16(v0); s.y = f32_bf16(v1); s.z = f32_bf16(v2); s.w = f32_bf16(v3);
    *(short4*)(&lds_u[r * LDS_STRIDE + c4 * 4]) = s;
  }
  __syncthreads();

  // ---- B fragments: Toeplitz tap matrix B[k][n] = w(k-n), w(i)=kern[180-i] (zero outside)
  // Shift-invariant across n-tiles -> computed once, held in registers.
  bf16x8 bfrag[NCHUNK];
  #pragma unroll
  for (int c = 0; c < NCHUNK; ++c) {
    #pragma unroll
    for (int j = 0; j < 8; ++j) {
      int idx = 32 * c + quad * 8 + j - nn;    // k - n
      float v = (idx >= 0 && idx < kKt) ? lds_k[kKt - 1 - idx] : 0.0f;
      bfrag[c][j] = f32_bf16(v);
    }
  }

  // ---- compute: each wave -> 128 outputs = 8 n-tiles of 16
  const short* arow = &lds_u[nn * LDS_STRIDE + quad * 8];
  #pragma unroll 2
  for (int jt = 0; jt < BT / 64; ++jt) {
    const int nt = wave * (BT / 4) + jt * 16;
    f32x4 acc = {0.f, 0.f, 0.f, 0.f};
    #pragma unroll
    for (int c = 0; c < NCHUNK; ++c) {
      bf16x8 a = *(const bf16x8*)(arow + nt + 32 * c);
      acc = __builtin_amdgcn_mfma_f32_16x16x32_bf16(a, bfrag[c], acc, 0, 0, 0);
    }
    const int gt = t0 + nt + nn;
    #pragma unroll
    for (int r = 0; r < 4; ++r) {
      const int gb = b0 + quad * 4 + r;
      if (gb < kB && gt < kT) out[(size_t)gb * kT + gt] = acc[r];
    }
  }
}

extern "C" void kernel_launch(void* const* d_in, const int* in_sizes, int n_in,
                              void* d_out, int out_size, void* d_ws, size_t ws_size,
                              hipStream_t stream) {
  const float* u  = (const float*)d_in[0];
  const float* kn = (const float*)d_in[1];
  float* out = (float*)d_out;
  dim3 grid((kT + BT - 1) / BT, (kB + BM - 1) / BM);
  hipLaunchKernelGGL(biexp_conv_mfma, grid, dim3(256, 1, 1), 0, stream, u, kn, out);
}